// Round 8
// baseline (222.515 us; speedup 1.0000x reference)
//
#include <hip/hip_runtime.h>
#include <hip/hip_bf16.h>
#include <stdint.h>

typedef unsigned short u16;
typedef __bf16 bf16x8 __attribute__((ext_vector_type(8)));
typedef float f32x4 __attribute__((ext_vector_type(4)));

// E=8, D=512, H=256, T=64, B=16384

__device__ __forceinline__ u16 f2bf(float f) {
  unsigned int u = __builtin_bit_cast(unsigned int, f);
  u += 0x7fffu + ((u >> 16) & 1u);   // RNE (finite inputs)
  return (u16)(u >> 16);
}

// ---------------- prep: weight conversion only ----------------
__global__ __launch_bounds__(256) void prep_w(
    const float* __restrict__ We, const float* __restrict__ Wt,
    const float* __restrict__ Wg,
    u16* __restrict__ We_bf, u16* __restrict__ Wt_bf,
    u16* __restrict__ Wg_hi, u16* __restrict__ Wg_lo) {
  const int bx = blockIdx.x;
  if (bx < 520) {
    const float* src; u16* dst;
    if (bx < 512) { int base = bx * 2048 + threadIdx.x * 8; src = We + base; dst = We_bf + base; }
    else { int base = (bx - 512) * 2048 + threadIdx.x * 8; src = Wt + base; dst = Wt_bf + base; }
    float4 a = *(const float4*)src;
    float4 b = *(const float4*)(src + 4);
    uint4 o;
    o.x = (unsigned)f2bf(a.x) | ((unsigned)f2bf(a.y) << 16);
    o.y = (unsigned)f2bf(a.z) | ((unsigned)f2bf(a.w) << 16);
    o.z = (unsigned)f2bf(b.x) | ((unsigned)f2bf(b.y) << 16);
    o.w = (unsigned)f2bf(b.z) | ((unsigned)f2bf(b.w) << 16);
    *(uint4*)dst = o;
  } else {
    int base = (bx - 520) * 2048 + threadIdx.x * 8;
    float x[8];
    float4 a = *(const float4*)(Wg + base);
    float4 b = *(const float4*)(Wg + base + 4);
    x[0]=a.x; x[1]=a.y; x[2]=a.z; x[3]=a.w; x[4]=b.x; x[5]=b.y; x[6]=b.z; x[7]=b.w;
    u16 h[8], l[8];
#pragma unroll
    for (int j = 0; j < 8; j++) {
      h[j] = f2bf(x[j]);
      float hf = __builtin_bit_cast(float, ((unsigned)h[j]) << 16);
      l[j] = f2bf(x[j] - hf);
    }
    uint4 oh, ol;
    oh.x = (unsigned)h[0] | ((unsigned)h[1] << 16);
    oh.y = (unsigned)h[2] | ((unsigned)h[3] << 16);
    oh.z = (unsigned)h[4] | ((unsigned)h[5] << 16);
    oh.w = (unsigned)h[6] | ((unsigned)h[7] << 16);
    ol.x = (unsigned)l[0] | ((unsigned)l[1] << 16);
    ol.y = (unsigned)l[2] | ((unsigned)l[3] << 16);
    ol.z = (unsigned)l[4] | ((unsigned)l[5] << 16);
    ol.w = (unsigned)l[6] | ((unsigned)l[7] << 16);
    *(uint4*)(Wg_hi + base) = oh;
    *(uint4*)(Wg_lo + base) = ol;
  }
}

// ---------------- fused main kernel ----------------
// grid = 512 (32-row m-tiles, FULL H=256), 256 threads = 4 waves, wave w
// owns the 64-col band [w*64, w*64+64).
//
// r7 post-mortem: the LDS-B pipeline (128 fine barrier phases/block,
// stage->consume distance ~130cy < L2 latency) pinned MfmaUtil at 18% with
// nothing saturated. LDS multicast of B only pays across MANY waves; with 4
// waves/block the L2 B-traffic (4 MB/CU) is invariant staged-or-not. So:
// B is read DIRECTLY from global (L2-resident, We_bf = 2 MB/XCD-L2) into
// registers -> the expert loop has ZERO barriers, zero LDS-B transit, zero
// vmcnt choreography. Waves drift freely; L2 latency hidden by ILP (64
// independent 16B loads per expert per wave, compiler hoists) + 8 waves/CU;
// co-resident block's matching wave reads identical B lines -> L1 reuse.
// A (xv) stays in LDS (32 KB, XOR-swizzled, written once by wave 0 —
// reg-resident A spilled in r1-r5; LDS-A since r7 has WRITE_SIZE at ideal).
__global__ __launch_bounds__(256, 2) void moe_main(
    const float* __restrict__ xv, const u16* __restrict__ We_bf,
    const float* __restrict__ be, const float* __restrict__ bg,
    const u16* __restrict__ Wg_hi, const u16* __restrict__ Wg_lo,
    const u16* __restrict__ Wt_bf, const float* __restrict__ bt,
    float* __restrict__ out) {
  __shared__ u16 lds[16384];            // 32 KB: A-tile; reused for comb/tower

  const int tid = threadIdx.x;
  const int lane = tid & 63;
  const int wid = tid >> 6;             // 0..3
  const int wn = wid;                   // 64-col band
  const int l15 = lane & 15;
  const int l4 = lane >> 4;             // 0..3
  const int m0 = blockIdx.x << 5;       // 32 rows per block

  // ---- prologue: A f32 -> bf16 into LDS (wave 0) + gate via hi/lo MFMA ----
  // All waves convert (each needs gate logits: same 32 rows, per-lane frags
  // feed the fold's __shfl); only wave 0 writes the A-tile.
  f32x4 g0[2] = {{0.f,0.f,0.f,0.f},{0.f,0.f,0.f,0.f}};
  f32x4 g1[2] = {{0.f,0.f,0.f,0.f},{0.f,0.f,0.f,0.f}};
  f32x4 g2[2] = {{0.f,0.f,0.f,0.f},{0.f,0.f,0.f,0.f}};
  const int esrc = l15 & 7;
#pragma unroll
  for (int mt = 0; mt < 2; mt++) {
#pragma unroll
    for (int ks = 0; ks < 16; ks++) {
      const int row = mt * 16 + l15;
      const float* ap = xv + ((m0 + row) << 9) + ks * 32 + l4 * 8;
      float4 xa = *(const float4*)ap;
      float4 xb = *(const float4*)(ap + 4);
      float x[8];
      x[0]=xa.x; x[1]=xa.y; x[2]=xa.z; x[3]=xa.w; x[4]=xb.x; x[5]=xb.y; x[6]=xb.z; x[7]=xb.w;
      bf16x8 hv, lv;
#pragma unroll
      for (int j = 0; j < 8; j++) {
        u16 hb_ = f2bf(x[j]);
        float hf = __builtin_bit_cast(float, ((unsigned)hb_) << 16);
        hv[j] = __builtin_bit_cast(__bf16, hb_);
        lv[j] = __builtin_bit_cast(__bf16, f2bf(x[j] - hf));
      }
      if (wid == 0) {
        int gA = ks * 4 + l4;           // 0..63 k-granule
        int slotA = (gA & ~7) | ((gA & 7) ^ (row & 7));
        *(bf16x8*)&lds[(row << 9) + (slotA << 3)] = hv;
      }
      bf16x8 wh = *(const bf16x8*)(Wg_hi + (esrc << 9) + ks * 32 + l4 * 8);
      bf16x8 wl = *(const bf16x8*)(Wg_lo + (esrc << 9) + ks * 32 + l4 * 8);
      g0[mt] = __builtin_amdgcn_mfma_f32_16x16x32_bf16(hv, wh, g0[mt], 0, 0, 0);
      g1[mt] = __builtin_amdgcn_mfma_f32_16x16x32_bf16(lv, wh, g1[mt], 0, 0, 0);
      g2[mt] = __builtin_amdgcn_mfma_f32_16x16x32_bf16(hv, wl, g2[mt], 0, 0, 0);
    }
  }
  // softmax over experts (lane holds logit[row=l4*4+i][e=l15&7])
  float gv[2][4];
  {
    float bgv = bg[esrc];
#pragma unroll
    for (int mt = 0; mt < 2; mt++)
#pragma unroll
      for (int i = 0; i < 4; i++) {
        float z = g0[mt][i] + g1[mt][i] + g2[mt][i] + bgv;
        float mx = z;
        mx = fmaxf(mx, __shfl_xor(mx, 1));
        mx = fmaxf(mx, __shfl_xor(mx, 2));
        mx = fmaxf(mx, __shfl_xor(mx, 4));
        float p = __expf(z - mx);
        float s = p;
        s += __shfl_xor(s, 1);
        s += __shfl_xor(s, 2);
        s += __shfl_xor(s, 4);
        gv[mt][i] = p / s;
      }
  }
  __syncthreads();                      // publish A-tile

  // ---- expert loop: BARRIER-FREE. B direct from global, A-frags from LDS --
  f32x4 comb[2][4];
#pragma unroll
  for (int mt = 0; mt < 2; mt++)
#pragma unroll
    for (int nt = 0; nt < 4; nt++) comb[mt][nt] = {0.f, 0.f, 0.f, 0.f};

#pragma unroll 1
  for (int e = 0; e < 8; e++) {
    f32x4 acc[2][4];
#pragma unroll
    for (int mt = 0; mt < 2; mt++)
#pragma unroll
      for (int nt = 0; nt < 4; nt++) acc[mt][nt] = {0.f, 0.f, 0.f, 0.f};

    // per-lane B base: row (wn*64 + l15), k-offset l4*8
    const u16* Be = We_bf + (e << 17) + ((wn * 64 + l15) << 9) + l4 * 8;
#pragma unroll
    for (int kc = 0; kc < 16; kc++) {   // K granule of 32; 64 indep B loads/e
      bf16x8 af0, af1;
      {
        int gA = kc * 4 + l4;
        int sl = (gA & ~7) | ((gA & 7) ^ (l15 & 7));   // (row&7)==(l15&7)
        af0 = *(const bf16x8*)&lds[(l15 << 9) + (sl << 3)];
        af1 = *(const bf16x8*)&lds[((16 + l15) << 9) + (sl << 3)];
      }
#pragma unroll
      for (int nt = 0; nt < 4; nt++) {
        bf16x8 bfr = *(const bf16x8*)(Be + (nt << 13) + kc * 32);
        acc[0][nt] = __builtin_amdgcn_mfma_f32_16x16x32_bf16(af0, bfr, acc[0][nt], 0, 0, 0);
        acc[1][nt] = __builtin_amdgcn_mfma_f32_16x16x32_bf16(af1, bfr, acc[1][nt], 0, 0, 0);
      }
    }
    // fold: comb += gate[row,e] * relu(acc + be[e,h])
    float bev[4];
#pragma unroll
    for (int nt = 0; nt < 4; nt++)
      bev[nt] = be[(e << 8) + wn * 64 + nt * 16 + l15];
#pragma unroll
    for (int mt = 0; mt < 2; mt++)
#pragma unroll
      for (int i = 0; i < 4; i++) {
        float g = __shfl(gv[mt][i], (lane & 48) | e);
#pragma unroll
        for (int nt = 0; nt < 4; nt++)
          comb[mt][nt][i] += g * fmaxf(acc[mt][nt][i] + bev[nt], 0.f);
      }
  }

  // ---- tower: comb[32x256] (bf16 via LDS, reusing A region) ----
  __syncthreads();                      // all waves done reading A-tile
#pragma unroll
  for (int mt = 0; mt < 2; mt++)
#pragma unroll
    for (int i = 0; i < 4; i++) {
      int row = mt * 16 + l4 * 4 + i;
#pragma unroll
      for (int nt = 0; nt < 4; nt++) {
        int col = wn * 64 + nt * 16 + l15;
        __bf16 v = (__bf16)comb[mt][nt][i];
        lds[row * 264 + col] = __builtin_bit_cast(u16, v);   // pad 264
      }
    }
  __syncthreads();
  if (wid < 2) {
    f32x4 tacc[4];
#pragma unroll
    for (int nt = 0; nt < 4; nt++) tacc[nt] = {0.f, 0.f, 0.f, 0.f};
#pragma unroll
    for (int ks = 0; ks < 8; ks++) {
      bf16x8 aT = *(const bf16x8*)&lds[(wid * 16 + l15) * 264 + ks * 32 + l4 * 8];
#pragma unroll
      for (int nt = 0; nt < 4; nt++) {
        bf16x8 bT = *(const bf16x8*)&Wt_bf[(nt * 16 + l15) * 256 + ks * 32 + l4 * 8];
        tacc[nt] = __builtin_amdgcn_mfma_f32_16x16x32_bf16(aT, bT, tacc[nt], 0, 0, 0);
      }
    }
#pragma unroll
    for (int nt = 0; nt < 4; nt++) {
      float btv = bt[nt * 16 + l15];
#pragma unroll
      for (int i = 0; i < 4; i++) {
        int row = m0 + wid * 16 + l4 * 4 + i;
        float v = tacc[nt][i] + btv;
        out[row * 64 + nt * 16 + l15] = 1.f / (1.f + __expf(-v));
      }
    }
  }
}

extern "C" void kernel_launch(void* const* d_in, const int* in_sizes, int n_in,
                              void* d_out, int out_size, void* d_ws, size_t ws_size,
                              hipStream_t stream) {
  const float* xv = (const float*)d_in[0];
  const float* We = (const float*)d_in[1];
  const float* be = (const float*)d_in[2];
  const float* Wg = (const float*)d_in[3];
  const float* bg = (const float*)d_in[4];
  const float* Wt = (const float*)d_in[5];
  const float* bt = (const float*)d_in[6];

  char* ws = (char*)d_ws;
  u16* We_bf = (u16*)ws;                        // 2 MB   (8*256*512 bf16)
  u16* Wt_bf = (u16*)(ws + 2097152);            // 32 KB  (64*256 bf16)
  u16* Wg_hi = (u16*)(ws + 2129920);            // 8 KB   (8*512 bf16)
  u16* Wg_lo = (u16*)(ws + 2138112);            // 8 KB

  prep_w<<<522, 256, 0, stream>>>(We, Wt, Wg, We_bf, Wt_bf, Wg_hi, Wg_lo);
  moe_main<<<512, 256, 0, stream>>>(xv, We_bf, be, bg, Wg_hi, Wg_lo, Wt_bf, bt,
                                    (float*)d_out);
}